// Round 1
// baseline (2832.161 us; speedup 1.0000x reference)
//
#include <hip/hip_runtime.h>

#define NN 50000
#define EE 800000
#define FIN 128
#define NHEAD 8
#define C1 64       // NHEAD * HID
#define C2 32
#define NEG 0.2f
#define NG 64

// ---------- helpers ----------
__device__ __forceinline__ unsigned fenc(float f) {
    unsigned u = __float_as_uint(f);
    return (u & 0x80000000u) ? ~u : (u | 0x80000000u);
}
__device__ __forceinline__ float fdec(unsigned u) {
    return (u & 0x80000000u) ? __uint_as_float(u & 0x7fffffffu)
                             : __uint_as_float(~u);
}
__device__ __forceinline__ float lrelu(float x) { return x > 0.f ? x : NEG * x; }

// ---------- GEMM1: h1 = x @ W1 ; al1_s/al1_d fused ----------
__global__ __launch_bounds__(256) void gemm1(const float* __restrict__ x,
                                             const float* __restrict__ W1,
                                             const float* __restrict__ a1s,
                                             const float* __restrict__ a1d,
                                             float* __restrict__ h1,
                                             float* __restrict__ al1s,
                                             float* __restrict__ al1d) {
    __shared__ float sW[128 * 64];   // 32 KB
    __shared__ float sx[16 * 128];   // 8 KB
    const int t = threadIdx.x;
    for (int i = t; i < 128 * 64; i += 256) sW[i] = W1[i];
    const int row0 = blockIdx.x * 16;
    for (int i = t; i < 16 * 128; i += 256) {
        int r = row0 + (i >> 7);
        sx[i] = (r < NN) ? x[(size_t)r * 128 + (i & 127)] : 0.f;
    }
    __syncthreads();
    const int w = t >> 6, lane = t & 63;
    float acc[4] = {0.f, 0.f, 0.f, 0.f};
    const int rbase = w * 4;
    for (int k = 0; k < 128; ++k) {
        float wv = sW[k * 64 + lane];
#pragma unroll
        for (int r = 0; r < 4; ++r) acc[r] += sx[(rbase + r) * 128 + k] * wv;
    }
    const float as = a1s[lane], ad = a1d[lane];  // a1_src[h][c] flat == lane
#pragma unroll
    for (int r = 0; r < 4; ++r) {
        int row = row0 + rbase + r;       // wave-uniform
        if (row >= NN) continue;
        h1[(size_t)row * 64 + lane] = acc[r];
        float ps = acc[r] * as, pd = acc[r] * ad;
#pragma unroll
        for (int off = 1; off < 8; off <<= 1) {
            ps += __shfl_xor(ps, off);
            pd += __shfl_xor(pd, off);
        }
        if ((lane & 7) == 0) {
            al1s[row * 8 + (lane >> 3)] = ps;
            al1d[row * 8 + (lane >> 3)] = pd;
        }
    }
}

// ---------- layer-1 edge passes ----------
__global__ __launch_bounds__(256) void emax1(const int* __restrict__ ei,
                                             const float* __restrict__ al1s,
                                             const float* __restrict__ al1d,
                                             unsigned* __restrict__ m1) {
    long long idx = (long long)blockIdx.x * 256 + threadIdx.x;
    if (idx >= (long long)(EE + NN) * 8) return;
    int h = (int)(idx & 7);
    int e = (int)(idx >> 3);
    int s, d;
    if (e < EE) { s = ei[e]; d = ei[EE + e]; } else { s = d = e - EE; }
    float v = lrelu(al1s[s * 8 + h] + al1d[d * 8 + h]);
    atomicMax(&m1[d * 8 + h], fenc(v));
}

__global__ __launch_bounds__(256) void esum1(const int* __restrict__ ei,
                                             const float* __restrict__ al1s,
                                             const float* __restrict__ al1d,
                                             const unsigned* __restrict__ m1,
                                             float* __restrict__ d1) {
    long long idx = (long long)blockIdx.x * 256 + threadIdx.x;
    if (idx >= (long long)(EE + NN) * 8) return;
    int h = (int)(idx & 7);
    int e = (int)(idx >> 3);
    int s, d;
    if (e < EE) { s = ei[e]; d = ei[EE + e]; } else { s = d = e - EE; }
    float v = lrelu(al1s[s * 8 + h] + al1d[d * 8 + h]);
    atomicAdd(&d1[d * 8 + h], expf(v - fdec(m1[d * 8 + h])));
}

__global__ __launch_bounds__(256) void escat1(const int* __restrict__ ei,
                                              const float* __restrict__ al1s,
                                              const float* __restrict__ al1d,
                                              const unsigned* __restrict__ m1,
                                              const float* __restrict__ d1,
                                              const float* __restrict__ h1,
                                              float* __restrict__ out1) {
    long long idx = (long long)blockIdx.x * 256 + threadIdx.x;
    if (idx >= (long long)(EE + NN) * 8) return;
    int h = (int)(idx & 7);
    int e = (int)(idx >> 3);
    int s, d;
    if (e < EE) { s = ei[e]; d = ei[EE + e]; } else { s = d = e - EE; }
    float v = lrelu(al1s[s * 8 + h] + al1d[d * 8 + h]);
    float ex = expf(v - fdec(m1[d * 8 + h]));
    float alpha = ex / (d1[d * 8 + h] + 1e-16f);
    const float4* hp = (const float4*)(h1 + (size_t)s * 64 + h * 8);
    float4 f0 = hp[0], f1 = hp[1];
    float* op = out1 + (size_t)d * 64 + h * 8;
    atomicAdd(op + 0, alpha * f0.x);
    atomicAdd(op + 1, alpha * f0.y);
    atomicAdd(op + 2, alpha * f0.z);
    atomicAdd(op + 3, alpha * f0.w);
    atomicAdd(op + 4, alpha * f1.x);
    atomicAdd(op + 5, alpha * f1.y);
    atomicAdd(op + 6, alpha * f1.z);
    atomicAdd(op + 7, alpha * f1.w);
}

// ---------- GEMM2: h2 = elu(out1 + b1) @ W2 ; al2_s/al2_d fused ----------
__global__ __launch_bounds__(256) void gemm2(const float* __restrict__ out1,
                                             const float* __restrict__ b1,
                                             const float* __restrict__ W2,
                                             const float* __restrict__ a2s,
                                             const float* __restrict__ a2d,
                                             float* __restrict__ h2,
                                             float* __restrict__ al2s,
                                             float* __restrict__ al2d) {
    __shared__ float sW[64 * 32];  // 8 KB
    __shared__ float st[8 * 64];   // 2 KB
    const int t = threadIdx.x;
    for (int i = t; i < 64 * 32; i += 256) sW[i] = W2[i];
    const int row0 = blockIdx.x * 8;
    for (int i = t; i < 8 * 64; i += 256) {
        int r = row0 + (i >> 6);
        int k = i & 63;
        float v = (r < NN) ? out1[(size_t)r * 64 + k] + b1[k] : 0.f;
        st[i] = v > 0.f ? v : (expf(v) - 1.f);   // elu
    }
    __syncthreads();
    const int w = t >> 6, lane = t & 63;
    const int rr = lane >> 5, c = lane & 31;
    const int lrow = w * 2 + rr;
    const int row = row0 + lrow;
    float acc = 0.f;
    for (int k = 0; k < 64; ++k) acc += st[lrow * 64 + k] * sW[k * 32 + c];
    if (row < NN) {
        h2[(size_t)row * 32 + c] = acc;
        float ps = acc * a2s[c], pd = acc * a2d[c];
#pragma unroll
        for (int off = 1; off < 32; off <<= 1) {
            ps += __shfl_xor(ps, off);
            pd += __shfl_xor(pd, off);
        }
        if (c == 0) { al2s[row] = ps; al2d[row] = pd; }
    }
}

// ---------- layer-2 edge passes (1 head, 32 ch) ----------
__global__ __launch_bounds__(256) void emax2(const int* __restrict__ ei,
                                             const float* __restrict__ al2s,
                                             const float* __restrict__ al2d,
                                             unsigned* __restrict__ m2) {
    long long idx = (long long)blockIdx.x * 256 + threadIdx.x;
    if (idx >= (long long)(EE + NN)) return;
    int e = (int)idx;
    int s, d;
    if (e < EE) { s = ei[e]; d = ei[EE + e]; } else { s = d = e - EE; }
    float v = lrelu(al2s[s] + al2d[d]);
    atomicMax(&m2[d], fenc(v));
}

__global__ __launch_bounds__(256) void esum2(const int* __restrict__ ei,
                                             const float* __restrict__ al2s,
                                             const float* __restrict__ al2d,
                                             const unsigned* __restrict__ m2,
                                             float* __restrict__ d2) {
    long long idx = (long long)blockIdx.x * 256 + threadIdx.x;
    if (idx >= (long long)(EE + NN)) return;
    int e = (int)idx;
    int s, d;
    if (e < EE) { s = ei[e]; d = ei[EE + e]; } else { s = d = e - EE; }
    float v = lrelu(al2s[s] + al2d[d]);
    atomicAdd(&d2[d], expf(v - fdec(m2[d])));
}

__global__ __launch_bounds__(256) void escat2(const int* __restrict__ ei,
                                              const float* __restrict__ al2s,
                                              const float* __restrict__ al2d,
                                              const unsigned* __restrict__ m2,
                                              const float* __restrict__ d2,
                                              const float* __restrict__ h2,
                                              float* __restrict__ out2) {
    long long idx = (long long)blockIdx.x * 256 + threadIdx.x;
    if (idx >= (long long)(EE + NN) * 4) return;
    int q = (int)(idx & 3);
    int e = (int)(idx >> 2);
    int s, d;
    if (e < EE) { s = ei[e]; d = ei[EE + e]; } else { s = d = e - EE; }
    float v = lrelu(al2s[s] + al2d[d]);
    float ex = expf(v - fdec(m2[d]));
    float alpha = ex / (d2[d] + 1e-16f);
    const float4* hp = (const float4*)(h2 + (size_t)s * 32 + q * 8);
    float4 f0 = hp[0], f1 = hp[1];
    float* op = out2 + (size_t)d * 32 + q * 8;
    atomicAdd(op + 0, alpha * f0.x);
    atomicAdd(op + 1, alpha * f0.y);
    atomicAdd(op + 2, alpha * f0.z);
    atomicAdd(op + 3, alpha * f0.w);
    atomicAdd(op + 4, alpha * f1.x);
    atomicAdd(op + 5, alpha * f1.y);
    atomicAdd(op + 6, alpha * f1.z);
    atomicAdd(op + 7, alpha * f1.w);
}

// ---------- pooling ----------
__global__ __launch_bounds__(256) void pool(const float* __restrict__ out2,
                                            const float* __restrict__ b2,
                                            const int* __restrict__ batch,
                                            float* __restrict__ psum,
                                            float* __restrict__ pcnt) {
    long long idx = (long long)blockIdx.x * 256 + threadIdx.x;
    if (idx >= (long long)NN * 32) return;
    int n = (int)(idx >> 5);
    int c = (int)(idx & 31);
    float v = out2[(size_t)n * 32 + c] + b2[c];
    int g = batch[n];
    atomicAdd(&psum[g * 32 + c], v);
    if (c == 0) atomicAdd(&pcnt[g], 1.0f);
}

__global__ __launch_bounds__(128) void final_lin(const float* __restrict__ psum,
                                                 const float* __restrict__ pcnt,
                                                 const float* __restrict__ Wlin,
                                                 const float* __restrict__ blin,
                                                 float* __restrict__ out) {
    int t = threadIdx.x;
    if (t >= NG * 2) return;
    int g = t >> 1, j = t & 1;
    float cnt = fmaxf(pcnt[g], 1.0f);
    float acc = blin[j];
    for (int c = 0; c < 32; ++c) acc += (psum[g * 32 + c] / cnt) * Wlin[c * 2 + j];
    out[g * 2 + j] = acc;
}

// ---------- launch ----------
static inline size_t alignup(size_t x) { return (x + 255) & ~(size_t)255; }

extern "C" void kernel_launch(void* const* d_in, const int* in_sizes, int n_in,
                              void* d_out, int out_size, void* d_ws, size_t ws_size,
                              hipStream_t stream) {
    const float* x    = (const float*)d_in[0];
    const int*   ei   = (const int*)d_in[1];
    const int*   batch= (const int*)d_in[2];
    const float* W1   = (const float*)d_in[3];
    const float* a1s  = (const float*)d_in[4];
    const float* a1d  = (const float*)d_in[5];
    const float* b1   = (const float*)d_in[6];
    const float* W2   = (const float*)d_in[7];
    const float* a2s  = (const float*)d_in[8];
    const float* a2d  = (const float*)d_in[9];
    const float* b2   = (const float*)d_in[10];
    const float* Wlin = (const float*)d_in[11];
    const float* blin = (const float*)d_in[12];
    float* out = (float*)d_out;
    char* ws = (char*)d_ws;

    size_t o = 0;
    // ---- zeroed region (accumulators) ----
    size_t OUT1 = o; o += alignup((size_t)NN * 64 * 4);
    size_t M1   = o; o += alignup((size_t)NN * 8 * 4);
    size_t D1   = o; o += alignup((size_t)NN * 8 * 4);
    size_t OUT2 = o; o += alignup((size_t)NN * 32 * 4);
    size_t M2   = o; o += alignup((size_t)NN * 4);
    size_t D2   = o; o += alignup((size_t)NN * 4);
    size_t PSUM = o; o += alignup((size_t)NG * 32 * 4);
    size_t PCNT = o; o += alignup((size_t)NG * 4);
    size_t zero_bytes = o;
    // ---- overwritten region ----
    size_t H1   = o; o += alignup((size_t)NN * 64 * 4);
    size_t AL1S = o; o += alignup((size_t)NN * 8 * 4);
    size_t AL1D = o; o += alignup((size_t)NN * 8 * 4);
    size_t H2   = o; o += alignup((size_t)NN * 32 * 4);
    size_t AL2S = o; o += alignup((size_t)NN * 4);
    size_t AL2D = o; o += alignup((size_t)NN * 4);
    (void)ws_size; (void)in_sizes; (void)n_in; (void)out_size;

    float*    out1 = (float*)(ws + OUT1);
    unsigned* m1   = (unsigned*)(ws + M1);
    float*    d1   = (float*)(ws + D1);
    float*    out2 = (float*)(ws + OUT2);
    unsigned* m2   = (unsigned*)(ws + M2);
    float*    d2   = (float*)(ws + D2);
    float*    psum = (float*)(ws + PSUM);
    float*    pcnt = (float*)(ws + PCNT);
    float*    h1   = (float*)(ws + H1);
    float*    al1s = (float*)(ws + AL1S);
    float*    al1d = (float*)(ws + AL1D);
    float*    h2   = (float*)(ws + H2);
    float*    al2s = (float*)(ws + AL2S);
    float*    al2d = (float*)(ws + AL2D);

    hipMemsetAsync(ws, 0, zero_bytes, stream);

    gemm1<<<NN / 16, 256, 0, stream>>>(x, W1, a1s, a1d, h1, al1s, al1d);

    long long t1 = (long long)(EE + NN) * 8;
    int g1 = (int)((t1 + 255) / 256);
    emax1<<<g1, 256, 0, stream>>>(ei, al1s, al1d, m1);
    esum1<<<g1, 256, 0, stream>>>(ei, al1s, al1d, m1, d1);
    escat1<<<g1, 256, 0, stream>>>(ei, al1s, al1d, m1, d1, h1, out1);

    gemm2<<<NN / 8, 256, 0, stream>>>(out1, b1, W2, a2s, a2d, h2, al2s, al2d);

    long long t2 = (long long)(EE + NN);
    int g2 = (int)((t2 + 255) / 256);
    emax2<<<g2, 256, 0, stream>>>(ei, al2s, al2d, m2);
    esum2<<<g2, 256, 0, stream>>>(ei, al2s, al2d, m2, d2);
    int g3 = (int)((t2 * 4 + 255) / 256);
    escat2<<<g3, 256, 0, stream>>>(ei, al2s, al2d, m2, d2, h2, out2);

    long long t4 = (long long)NN * 32;
    int g4 = (int)((t4 + 255) / 256);
    pool<<<g4, 256, 0, stream>>>(out2, b2, batch, psum, pcnt);

    final_lin<<<1, 128, 0, stream>>>(psum, pcnt, Wlin, blin, out);
}

// Round 2
// 354.682 us; speedup vs baseline: 7.9851x; 7.9851x over previous
//
#include <hip/hip_runtime.h>

#define NN 50000
#define EE 800000
#define ETOT (EE + NN)     // edges + self-loops
#define NHEAD 8
#define C1 64
#define C2 32
#define NEG 0.2f
#define NG 64

__device__ __forceinline__ float lrelu(float x) { return x > 0.f ? x : NEG * x; }

// ---------- GEMM1: h1 = x @ W1 ; al1_s/al1_d fused ----------
__global__ __launch_bounds__(256) void gemm1(const float* __restrict__ x,
                                             const float* __restrict__ W1,
                                             const float* __restrict__ a1s,
                                             const float* __restrict__ a1d,
                                             float* __restrict__ h1,
                                             float* __restrict__ al1s,
                                             float* __restrict__ al1d) {
    __shared__ float sW[128 * 64];   // 32 KB
    __shared__ float sx[16 * 128];   // 8 KB
    const int t = threadIdx.x;
    for (int i = t; i < 128 * 64; i += 256) sW[i] = W1[i];
    const int row0 = blockIdx.x * 16;
    for (int i = t; i < 16 * 128; i += 256) {
        int r = row0 + (i >> 7);
        sx[i] = (r < NN) ? x[(size_t)r * 128 + (i & 127)] : 0.f;
    }
    __syncthreads();
    const int w = t >> 6, lane = t & 63;
    float acc[4] = {0.f, 0.f, 0.f, 0.f};
    const int rbase = w * 4;
    for (int k = 0; k < 128; ++k) {
        float wv = sW[k * 64 + lane];
#pragma unroll
        for (int r = 0; r < 4; ++r) acc[r] += sx[(rbase + r) * 128 + k] * wv;
    }
    const float as = a1s[lane], ad = a1d[lane];
#pragma unroll
    for (int r = 0; r < 4; ++r) {
        int row = row0 + rbase + r;
        if (row >= NN) continue;
        h1[(size_t)row * 64 + lane] = acc[r];
        float ps = acc[r] * as, pd = acc[r] * ad;
#pragma unroll
        for (int off = 1; off < 8; off <<= 1) {
            ps += __shfl_xor(ps, off);
            pd += __shfl_xor(pd, off);
        }
        if ((lane & 7) == 0) {
            al1s[row * 8 + (lane >> 3)] = ps;
            al1d[row * 8 + (lane >> 3)] = pd;
        }
    }
}

// ---------- CSR build ----------
__global__ __launch_bounds__(256) void hist(const int* __restrict__ ei,
                                            int* __restrict__ deg) {
    int e = blockIdx.x * 256 + threadIdx.x;
    if (e >= ETOT) return;
    int d = (e < EE) ? ei[EE + e] : e - EE;
    atomicAdd(&deg[d], 1);
}

// block-local exclusive scan (256 elems/block) + block sums
__global__ __launch_bounds__(256) void scan1(const int* __restrict__ deg,
                                             int* __restrict__ rowptr,
                                             int* __restrict__ bsum) {
    __shared__ int s[256];
    int t = threadIdx.x;
    int i = blockIdx.x * 256 + t;
    int v = (i < NN) ? deg[i] : 0;
    s[t] = v;
    __syncthreads();
    for (int off = 1; off < 256; off <<= 1) {
        int u = (t >= off) ? s[t - off] : 0;
        __syncthreads();
        s[t] += u;
        __syncthreads();
    }
    if (i < NN) rowptr[i] = s[t] - v;       // exclusive within block
    if (t == 255) bsum[blockIdx.x] = s[255];
}

__global__ __launch_bounds__(256) void scan2(int* __restrict__ bsum, int nb) {
    __shared__ int s[256];
    int t = threadIdx.x;
    int v = (t < nb) ? bsum[t] : 0;
    s[t] = v;
    __syncthreads();
    for (int off = 1; off < 256; off <<= 1) {
        int u = (t >= off) ? s[t - off] : 0;
        __syncthreads();
        s[t] += u;
        __syncthreads();
    }
    if (t < nb) bsum[t] = s[t] - v;         // exclusive block offsets
}

// add block offsets; finalize rowptr[NN]; zero deg for reuse as cursor
__global__ __launch_bounds__(256) void scan3(int* __restrict__ rowptr,
                                             const int* __restrict__ bsum,
                                             int* __restrict__ deg) {
    int i = blockIdx.x * 256 + threadIdx.x;
    if (i < NN) {
        rowptr[i] += bsum[i >> 8];
        deg[i] = 0;
    }
    if (i == NN) rowptr[NN] = ETOT;
}

__global__ __launch_bounds__(256) void fillcsr(const int* __restrict__ ei,
                                               const int* __restrict__ rowptr,
                                               int* __restrict__ cursor,
                                               int* __restrict__ csr) {
    int e = blockIdx.x * 256 + threadIdx.x;
    if (e >= ETOT) return;
    int s, d;
    if (e < EE) { s = ei[e]; d = ei[EE + e]; } else { s = d = e - EE; }
    int pos = atomicAdd(&cursor[d], 1);
    csr[rowptr[d] + pos] = s;
}

// ---------- layer-1 fused softmax + aggregate (gather, no atomics) ----------
// one wave per dst node
__global__ __launch_bounds__(256) void agg1(const int* __restrict__ rowptr,
                                            const int* __restrict__ csr,
                                            const float* __restrict__ al1s,
                                            const float* __restrict__ al1d,
                                            const float* __restrict__ h1,
                                            float* __restrict__ out1) {
    const int lane = threadIdx.x & 63;
    const int d = blockIdx.x * 4 + (threadIdx.x >> 6);
    if (d >= NN) return;
    const int beg = rowptr[d], end = rowptr[d + 1];
    // phases 1-2: lane handles head h = lane&7, edge slot = lane>>3 (8 edges in flight)
    const int h = lane & 7, slot = lane >> 3;
    const float ald = al1d[d * 8 + h];
    float m = -1e30f;
    for (int i = beg + slot; i < end; i += 8) {
        int s = csr[i];
        float v = lrelu(al1s[s * 8 + h] + ald);
        m = fmaxf(m, v);
    }
    m = fmaxf(m, __shfl_xor(m, 8));
    m = fmaxf(m, __shfl_xor(m, 16));
    m = fmaxf(m, __shfl_xor(m, 32));
    float den = 0.f;
    for (int i = beg + slot; i < end; i += 8) {
        int s = csr[i];
        float v = lrelu(al1s[s * 8 + h] + ald);
        den += expf(v - m);
    }
    den += __shfl_xor(den, 8);
    den += __shfl_xor(den, 16);
    den += __shfl_xor(den, 32);
    // phase 3: lane = output channel; head hh = lane>>3
    const int hh = lane >> 3;
    const float mh   = __shfl(m, hh);
    const float dh   = __shfl(den, hh);
    const float aldh = __shfl(ald, hh);
    const float inv  = 1.f / (dh + 1e-16f);
    float acc = 0.f;
    int i = beg;
    for (; i + 1 < end; i += 2) {
        int s0 = csr[i], s1 = csr[i + 1];
        float v0 = lrelu(al1s[s0 * 8 + hh] + aldh);
        float v1 = lrelu(al1s[s1 * 8 + hh] + aldh);
        float a0 = expf(v0 - mh) * inv;
        float a1 = expf(v1 - mh) * inv;
        acc += a0 * h1[(size_t)s0 * 64 + lane];
        acc += a1 * h1[(size_t)s1 * 64 + lane];
    }
    if (i < end) {
        int s0 = csr[i];
        float v0 = lrelu(al1s[s0 * 8 + hh] + aldh);
        acc += expf(v0 - mh) * inv * h1[(size_t)s0 * 64 + lane];
    }
    out1[(size_t)d * 64 + lane] = acc;
}

// ---------- GEMM2: h2 = elu(out1 + b1) @ W2 ; al2_s/al2_d fused ----------
__global__ __launch_bounds__(256) void gemm2(const float* __restrict__ out1,
                                             const float* __restrict__ b1,
                                             const float* __restrict__ W2,
                                             const float* __restrict__ a2s,
                                             const float* __restrict__ a2d,
                                             float* __restrict__ h2,
                                             float* __restrict__ al2s,
                                             float* __restrict__ al2d) {
    __shared__ float sW[64 * 32];
    __shared__ float st[8 * 64];
    const int t = threadIdx.x;
    for (int i = t; i < 64 * 32; i += 256) sW[i] = W2[i];
    const int row0 = blockIdx.x * 8;
    for (int i = t; i < 8 * 64; i += 256) {
        int r = row0 + (i >> 6);
        int k = i & 63;
        float v = (r < NN) ? out1[(size_t)r * 64 + k] + b1[k] : 0.f;
        st[i] = v > 0.f ? v : (expf(v) - 1.f);
    }
    __syncthreads();
    const int w = t >> 6, lane = t & 63;
    const int rr = lane >> 5, c = lane & 31;
    const int lrow = w * 2 + rr;
    const int row = row0 + lrow;
    float acc = 0.f;
    for (int k = 0; k < 64; ++k) acc += st[lrow * 64 + k] * sW[k * 32 + c];
    if (row < NN) {
        h2[(size_t)row * 32 + c] = acc;
        float ps = acc * a2s[c], pd = acc * a2d[c];
#pragma unroll
        for (int off = 1; off < 32; off <<= 1) {
            ps += __shfl_xor(ps, off);
            pd += __shfl_xor(pd, off);
        }
        if (c == 0) { al2s[row] = ps; al2d[row] = pd; }
    }
}

// ---------- layer-2 fused softmax + aggregate (gather, 1 head, 32 ch) ----------
__global__ __launch_bounds__(256) void agg2(const int* __restrict__ rowptr,
                                            const int* __restrict__ csr,
                                            const float* __restrict__ al2s,
                                            const float* __restrict__ al2d,
                                            const float* __restrict__ h2,
                                            float* __restrict__ out2) {
    const int lane = threadIdx.x & 63;
    const int d = blockIdx.x * 4 + (threadIdx.x >> 6);
    if (d >= NN) return;
    const int beg = rowptr[d], end = rowptr[d + 1];
    const float ald = al2d[d];
    float m = -1e30f;
    for (int i = beg + lane; i < end; i += 64) {
        int s = csr[i];
        m = fmaxf(m, lrelu(al2s[s] + ald));
    }
#pragma unroll
    for (int off = 32; off; off >>= 1) m = fmaxf(m, __shfl_xor(m, off));
    float den = 0.f;
    for (int i = beg + lane; i < end; i += 64) {
        int s = csr[i];
        den += expf(lrelu(al2s[s] + ald) - m);
    }
#pragma unroll
    for (int off = 32; off; off >>= 1) den += __shfl_xor(den, off);
    const float inv = 1.f / (den + 1e-16f);
    // phase 3: 2 edges x 32 channels
    const int sub = lane >> 5, c = lane & 31;
    float acc = 0.f;
    for (int i = beg + sub; i < end; i += 2) {
        int s = csr[i];
        float alpha = expf(lrelu(al2s[s] + ald) - m) * inv;
        acc += alpha * h2[(size_t)s * 32 + c];
    }
    acc += __shfl_xor(acc, 32);
    if (sub == 0) out2[(size_t)d * 32 + c] = acc;
}

// ---------- pooling (batch is sorted -> block-local LDS accumulation) ----------
__global__ __launch_bounds__(256) void pool(const float* __restrict__ out2,
                                            const float* __restrict__ b2,
                                            const int* __restrict__ batch,
                                            float* __restrict__ psum,
                                            float* __restrict__ pcnt) {
    __shared__ float sacc[8][32];
    __shared__ float scnt[8];
    const int t = threadIdx.x;
    const int c = t & 31, sl = t >> 5;
    const int n0 = blockIdx.x * 256;
    const int g0 = batch[n0 < NN ? n0 : NN - 1];
    float acc = 0.f, cnt = 0.f;
    for (int k = 0; k < 32; ++k) {
        int n = n0 + sl + 8 * k;
        if (n < NN) {
            float v = out2[(size_t)n * 32 + c] + b2[c];
            int g = batch[n];
            if (g == g0) {
                acc += v;
                if (c == 0) cnt += 1.f;
            } else {
                atomicAdd(&psum[g * 32 + c], v);
                if (c == 0) atomicAdd(&pcnt[g], 1.f);
            }
        }
    }
    sacc[sl][c] = acc;
    if (c == 0) scnt[sl] = cnt;
    __syncthreads();
    if (t < 32) {
        float s = 0.f;
        for (int j = 0; j < 8; ++j) s += sacc[j][t];
        atomicAdd(&psum[g0 * 32 + t], s);
        if (t == 0) {
            float sc = 0.f;
            for (int j = 0; j < 8; ++j) sc += scnt[j];
            atomicAdd(&pcnt[g0], sc);
        }
    }
}

__global__ __launch_bounds__(128) void final_lin(const float* __restrict__ psum,
                                                 const float* __restrict__ pcnt,
                                                 const float* __restrict__ Wlin,
                                                 const float* __restrict__ blin,
                                                 float* __restrict__ out) {
    int t = threadIdx.x;
    if (t >= NG * 2) return;
    int g = t >> 1, j = t & 1;
    float cnt = fmaxf(pcnt[g], 1.0f);
    float acc = blin[j];
    for (int c = 0; c < 32; ++c) acc += (psum[g * 32 + c] / cnt) * Wlin[c * 2 + j];
    out[g * 2 + j] = acc;
}

// ---------- launch ----------
static inline size_t alignup(size_t x) { return (x + 255) & ~(size_t)255; }

extern "C" void kernel_launch(void* const* d_in, const int* in_sizes, int n_in,
                              void* d_out, int out_size, void* d_ws, size_t ws_size,
                              hipStream_t stream) {
    const float* x    = (const float*)d_in[0];
    const int*   ei   = (const int*)d_in[1];
    const int*   batch= (const int*)d_in[2];
    const float* W1   = (const float*)d_in[3];
    const float* a1s  = (const float*)d_in[4];
    const float* a1d  = (const float*)d_in[5];
    const float* b1   = (const float*)d_in[6];
    const float* W2   = (const float*)d_in[7];
    const float* a2s  = (const float*)d_in[8];
    const float* a2d  = (const float*)d_in[9];
    const float* b2   = (const float*)d_in[10];
    const float* Wlin = (const float*)d_in[11];
    const float* blin = (const float*)d_in[12];
    float* out = (float*)d_out;
    char* ws = (char*)d_ws;
    (void)in_sizes; (void)n_in; (void)out_size; (void)ws_size;

    size_t o = 0;
    // ---- zeroed region ----
    size_t DEG  = o; o += alignup((size_t)NN * 4);          // deg, later reused as cursor
    size_t PSUM = o; o += alignup((size_t)NG * 32 * 4);
    size_t PCNT = o; o += alignup((size_t)NG * 4);
    size_t zero_bytes = o;
    // ---- overwritten region ----
    size_t ROWP = o; o += alignup((size_t)(NN + 1) * 4);
    size_t BSUM = o; o += alignup((size_t)256 * 4);
    size_t CSR  = o; o += alignup((size_t)ETOT * 4);
    size_t H1   = o; o += alignup((size_t)NN * 64 * 4);     // also reused as out2
    size_t AL1S = o; o += alignup((size_t)NN * 8 * 4);
    size_t AL1D = o; o += alignup((size_t)NN * 8 * 4);
    size_t OUT1 = o; o += alignup((size_t)NN * 64 * 4);
    size_t H2   = o; o += alignup((size_t)NN * 32 * 4);
    size_t AL2S = o; o += alignup((size_t)NN * 4);
    size_t AL2D = o; o += alignup((size_t)NN * 4);

    int*   deg    = (int*)(ws + DEG);
    float* psum   = (float*)(ws + PSUM);
    float* pcnt   = (float*)(ws + PCNT);
    int*   rowptr = (int*)(ws + ROWP);
    int*   bsum   = (int*)(ws + BSUM);
    int*   csr    = (int*)(ws + CSR);
    float* h1     = (float*)(ws + H1);
    float* al1s   = (float*)(ws + AL1S);
    float* al1d   = (float*)(ws + AL1D);
    float* out1   = (float*)(ws + OUT1);
    float* h2     = (float*)(ws + H2);
    float* al2s   = (float*)(ws + AL2S);
    float* al2d   = (float*)(ws + AL2D);
    float* out2   = h1;                      // alias: h1 dead after agg1

    hipMemsetAsync(ws, 0, zero_bytes, stream);

    gemm1<<<(NN + 15) / 16, 256, 0, stream>>>(x, W1, a1s, a1d, h1, al1s, al1d);

    const int gE = (ETOT + 255) / 256;
    const int nbScan = (NN + 255) / 256;          // 196
    hist<<<gE, 256, 0, stream>>>(ei, deg);
    scan1<<<nbScan, 256, 0, stream>>>(deg, rowptr, bsum);
    scan2<<<1, 256, 0, stream>>>(bsum, nbScan);
    scan3<<<(NN + 256) / 256, 256, 0, stream>>>(rowptr, bsum, deg);
    fillcsr<<<gE, 256, 0, stream>>>(ei, rowptr, deg, csr);

    const int gN = (NN + 3) / 4;
    agg1<<<gN, 256, 0, stream>>>(rowptr, csr, al1s, al1d, h1, out1);

    gemm2<<<(NN + 7) / 8, 256, 0, stream>>>(out1, b1, W2, a2s, a2d, h2, al2s, al2d);

    agg2<<<gN, 256, 0, stream>>>(rowptr, csr, al2s, al2d, h2, out2);

    pool<<<(NN + 255) / 256, 256, 0, stream>>>(out2, b2, batch, psum, pcnt);

    final_lin<<<1, 128, 0, stream>>>(psum, pcnt, Wlin, blin, out);
}

// Round 3
// 322.494 us; speedup vs baseline: 8.7821x; 1.0998x over previous
//
#include <hip/hip_runtime.h>

#define NN 50000
#define EE 800000
#define ETOT (EE + NN)     // edges + self-loops
#define NHEAD 8
#define C1 64
#define C2 32
#define NEG 0.2f
#define NG 64

__device__ __forceinline__ float lrelu(float x) { return x > 0.f ? x : NEG * x; }
__device__ __forceinline__ unsigned fenc(float f) {
    unsigned u = __float_as_uint(f);
    return (u & 0x80000000u) ? ~u : (u | 0x80000000u);
}
__device__ __forceinline__ float fdec(unsigned u) {
    return (u & 0x80000000u) ? __uint_as_float(u & 0x7fffffffu)
                             : __uint_as_float(~u);
}

// ---------- GEMM1: h1 = x @ W1 ; al1_s/al1_d fused ----------
__global__ __launch_bounds__(256) void gemm1(const float* __restrict__ x,
                                             const float* __restrict__ W1,
                                             const float* __restrict__ a1s,
                                             const float* __restrict__ a1d,
                                             float* __restrict__ h1,
                                             float* __restrict__ al1s,
                                             float* __restrict__ al1d) {
    __shared__ float sW[128 * 64];   // 32 KB
    __shared__ float sx[16 * 128];   // 8 KB
    const int t = threadIdx.x;
    for (int i = t; i < 128 * 64; i += 256) sW[i] = W1[i];
    const int row0 = blockIdx.x * 16;
    for (int i = t; i < 16 * 128; i += 256) {
        int r = row0 + (i >> 7);
        sx[i] = (r < NN) ? x[(size_t)r * 128 + (i & 127)] : 0.f;
    }
    __syncthreads();
    const int w = t >> 6, lane = t & 63;
    float acc[4] = {0.f, 0.f, 0.f, 0.f};
    const int rbase = w * 4;
    for (int k = 0; k < 128; ++k) {
        float wv = sW[k * 64 + lane];
#pragma unroll
        for (int r = 0; r < 4; ++r) acc[r] += sx[(rbase + r) * 128 + k] * wv;
    }
    const float as = a1s[lane], ad = a1d[lane];
#pragma unroll
    for (int r = 0; r < 4; ++r) {
        int row = row0 + rbase + r;
        if (row >= NN) continue;
        h1[(size_t)row * 64 + lane] = acc[r];
        float ps = acc[r] * as, pd = acc[r] * ad;
#pragma unroll
        for (int off = 1; off < 8; off <<= 1) {
            ps += __shfl_xor(ps, off);
            pd += __shfl_xor(pd, off);
        }
        if ((lane & 7) == 0) {
            al1s[row * 8 + (lane >> 3)] = ps;
            al1d[row * 8 + (lane >> 3)] = pd;
        }
    }
}

// ---------- CSR build ----------
__global__ __launch_bounds__(256) void hist(const int* __restrict__ ei,
                                            int* __restrict__ deg) {
    int e = blockIdx.x * 256 + threadIdx.x;
    if (e >= ETOT) return;
    int d = (e < EE) ? ei[EE + e] : e - EE;
    atomicAdd(&deg[d], 1);
}

__global__ __launch_bounds__(256) void scan1(const int* __restrict__ deg,
                                             int* __restrict__ rowptr,
                                             int* __restrict__ bsum) {
    __shared__ int s[256];
    int t = threadIdx.x;
    int i = blockIdx.x * 256 + t;
    int v = (i < NN) ? deg[i] : 0;
    s[t] = v;
    __syncthreads();
    for (int off = 1; off < 256; off <<= 1) {
        int u = (t >= off) ? s[t - off] : 0;
        __syncthreads();
        s[t] += u;
        __syncthreads();
    }
    if (i < NN) rowptr[i] = s[t] - v;
    if (t == 255) bsum[blockIdx.x] = s[255];
}

__global__ __launch_bounds__(256) void scan2(int* __restrict__ bsum, int nb) {
    __shared__ int s[256];
    int t = threadIdx.x;
    int v = (t < nb) ? bsum[t] : 0;
    s[t] = v;
    __syncthreads();
    for (int off = 1; off < 256; off <<= 1) {
        int u = (t >= off) ? s[t - off] : 0;
        __syncthreads();
        s[t] += u;
        __syncthreads();
    }
    if (t < nb) bsum[t] = s[t] - v;
}

__global__ __launch_bounds__(256) void scan3(int* __restrict__ rowptr,
                                             const int* __restrict__ bsum,
                                             int* __restrict__ deg) {
    int i = blockIdx.x * 256 + threadIdx.x;
    if (i < NN) {
        rowptr[i] += bsum[i >> 8];
        deg[i] = 0;
    }
    if (i == NN) rowptr[NN] = ETOT;
}

__global__ __launch_bounds__(256) void fillcsr(const int* __restrict__ ei,
                                               const int* __restrict__ rowptr,
                                               int* __restrict__ cursor,
                                               int* __restrict__ csr) {
    int e = blockIdx.x * 256 + threadIdx.x;
    if (e >= ETOT) return;
    int s, d;
    if (e < EE) { s = ei[e]; d = ei[EE + e]; } else { s = d = e - EE; }
    int pos = atomicAdd(&cursor[d], 1);
    csr[rowptr[d] + pos] = s;
}

// ---------- global per-head max of al1s (8 values) ----------
__global__ __launch_bounds__(256) void maxal1(const float* __restrict__ al1s,
                                              unsigned* __restrict__ gmax1) {
    const int t = blockIdx.x * 256 + threadIdx.x;   // grid = 98 blocks -> stride 25088 (mult of 8)
    const int h = t & 7;
    float m = -1e30f;
    for (int i = t; i < NN * 8; i += 98 * 256) m = fmaxf(m, al1s[i]);
    m = fmaxf(m, __shfl_xor(m, 8));
    m = fmaxf(m, __shfl_xor(m, 16));
    m = fmaxf(m, __shfl_xor(m, 32));
    if ((threadIdx.x & 63) < 8) atomicMax(&gmax1[h], fenc(m));
}

// ---------- global max of al2s (1 value) ----------
__global__ __launch_bounds__(256) void maxal2(const float* __restrict__ al2s,
                                              unsigned* __restrict__ gmax2) {
    const int t = blockIdx.x * 256 + threadIdx.x;
    float m = -1e30f;
    for (int i = t; i < NN; i += 98 * 256) m = fmaxf(m, al2s[i]);
#pragma unroll
    for (int off = 32; off; off >>= 1) m = fmaxf(m, __shfl_xor(m, off));
    if ((threadIdx.x & 63) == 0) atomicMax(gmax2, fenc(m));
}

// ---------- layer-1 fused softmax + aggregate: SINGLE edge pass ----------
__global__ __launch_bounds__(256) void agg1(const int* __restrict__ rowptr,
                                            const int* __restrict__ csr,
                                            const float* __restrict__ al1s,
                                            const float* __restrict__ al1d,
                                            const unsigned* __restrict__ gmax1,
                                            const float* __restrict__ h1,
                                            float* __restrict__ out1) {
    const int lane = threadIdx.x & 63;
    const int d = blockIdx.x * 4 + (threadIdx.x >> 6);
    if (d >= NN) return;
    const int beg = rowptr[d], end = rowptr[d + 1];
    const int hh = lane >> 3;                    // head for this channel
    const float ald = al1d[d * 8 + hh];
    const float M = lrelu(fdec(gmax1[hh]) + ald);   // upper bound on logits of this node/head
    float den = 0.f, acc = 0.f;
    int i = beg;
    for (; i + 1 < end; i += 2) {
        int s0 = csr[i], s1 = csr[i + 1];
        float a0 = __expf(lrelu(al1s[s0 * 8 + hh] + ald) - M);
        float a1 = __expf(lrelu(al1s[s1 * 8 + hh] + ald) - M);
        den += a0 + a1;
        acc += a0 * h1[(size_t)s0 * 64 + lane] + a1 * h1[(size_t)s1 * 64 + lane];
    }
    if (i < end) {
        int s0 = csr[i];
        float a0 = __expf(lrelu(al1s[s0 * 8 + hh] + ald) - M);
        den += a0;
        acc += a0 * h1[(size_t)s0 * 64 + lane];
    }
    out1[(size_t)d * 64 + lane] = acc / (den + 1e-16f);
}

// ---------- GEMM2: h2 = elu(out1 + b1) @ W2 ; al2_s/al2_d fused ----------
__global__ __launch_bounds__(256) void gemm2(const float* __restrict__ out1,
                                             const float* __restrict__ b1,
                                             const float* __restrict__ W2,
                                             const float* __restrict__ a2s,
                                             const float* __restrict__ a2d,
                                             float* __restrict__ h2,
                                             float* __restrict__ al2s,
                                             float* __restrict__ al2d) {
    __shared__ float sW[64 * 32];
    __shared__ float st[8 * 64];
    const int t = threadIdx.x;
    for (int i = t; i < 64 * 32; i += 256) sW[i] = W2[i];
    const int row0 = blockIdx.x * 8;
    for (int i = t; i < 8 * 64; i += 256) {
        int r = row0 + (i >> 6);
        int k = i & 63;
        float v = (r < NN) ? out1[(size_t)r * 64 + k] + b1[k] : 0.f;
        st[i] = v > 0.f ? v : (__expf(v) - 1.f);
    }
    __syncthreads();
    const int w = t >> 6, lane = t & 63;
    const int rr = lane >> 5, c = lane & 31;
    const int lrow = w * 2 + rr;
    const int row = row0 + lrow;
    float acc = 0.f;
    for (int k = 0; k < 64; ++k) acc += st[lrow * 64 + k] * sW[k * 32 + c];
    if (row < NN) {
        h2[(size_t)row * 32 + c] = acc;
        float ps = acc * a2s[c], pd = acc * a2d[c];
#pragma unroll
        for (int off = 1; off < 32; off <<= 1) {
            ps += __shfl_xor(ps, off);
            pd += __shfl_xor(pd, off);
        }
        if (c == 0) { al2s[row] = ps; al2d[row] = pd; }
    }
}

// ---------- layer-2 fused softmax + aggregate: SINGLE edge pass ----------
__global__ __launch_bounds__(256) void agg2(const int* __restrict__ rowptr,
                                            const int* __restrict__ csr,
                                            const float* __restrict__ al2s,
                                            const float* __restrict__ al2d,
                                            const unsigned* __restrict__ gmax2,
                                            const float* __restrict__ h2,
                                            float* __restrict__ out2) {
    const int lane = threadIdx.x & 63;
    const int d = blockIdx.x * 4 + (threadIdx.x >> 6);
    if (d >= NN) return;
    const int beg = rowptr[d], end = rowptr[d + 1];
    const float ald = al2d[d];
    const float M = lrelu(fdec(gmax2[0]) + ald);
    const int sub = lane >> 5, c = lane & 31;    // 2 edges x 32 channels
    float den = 0.f, acc = 0.f;
    for (int i = beg + sub; i < end; i += 2) {
        int s = csr[i];
        float a = __expf(lrelu(al2s[s] + ald) - M);
        den += a;
        acc += a * h2[(size_t)s * 32 + c];
    }
    den += __shfl_xor(den, 32);
    acc += __shfl_xor(acc, 32);
    if (sub == 0) out2[(size_t)d * 32 + c] = acc / (den + 1e-16f);
}

// ---------- pooling (batch sorted -> block-local LDS accumulation) ----------
__global__ __launch_bounds__(256) void pool(const float* __restrict__ out2,
                                            const float* __restrict__ b2,
                                            const int* __restrict__ batch,
                                            float* __restrict__ psum,
                                            float* __restrict__ pcnt) {
    __shared__ float sacc[8][32];
    __shared__ float scnt[8];
    const int t = threadIdx.x;
    const int c = t & 31, sl = t >> 5;
    const int n0 = blockIdx.x * 256;
    const int g0 = batch[n0 < NN ? n0 : NN - 1];
    float acc = 0.f, cnt = 0.f;
    for (int k = 0; k < 32; ++k) {
        int n = n0 + sl + 8 * k;
        if (n < NN) {
            float v = out2[(size_t)n * 32 + c] + b2[c];
            int g = batch[n];
            if (g == g0) {
                acc += v;
                if (c == 0) cnt += 1.f;
            } else {
                atomicAdd(&psum[g * 32 + c], v);
                if (c == 0) atomicAdd(&pcnt[g], 1.f);
            }
        }
    }
    sacc[sl][c] = acc;
    if (c == 0) scnt[sl] = cnt;
    __syncthreads();
    if (t < 32) {
        float s = 0.f;
        for (int j = 0; j < 8; ++j) s += sacc[j][t];
        atomicAdd(&psum[g0 * 32 + t], s);
        if (t == 0) {
            float sc = 0.f;
            for (int j = 0; j < 8; ++j) sc += scnt[j];
            atomicAdd(&pcnt[g0], sc);
        }
    }
}

__global__ __launch_bounds__(128) void final_lin(const float* __restrict__ psum,
                                                 const float* __restrict__ pcnt,
                                                 const float* __restrict__ Wlin,
                                                 const float* __restrict__ blin,
                                                 float* __restrict__ out) {
    int t = threadIdx.x;
    if (t >= NG * 2) return;
    int g = t >> 1, j = t & 1;
    float cnt = fmaxf(pcnt[g], 1.0f);
    float acc = blin[j];
    for (int c = 0; c < 32; ++c) acc += (psum[g * 32 + c] / cnt) * Wlin[c * 2 + j];
    out[g * 2 + j] = acc;
}

// ---------- launch ----------
static inline size_t alignup(size_t x) { return (x + 255) & ~(size_t)255; }

extern "C" void kernel_launch(void* const* d_in, const int* in_sizes, int n_in,
                              void* d_out, int out_size, void* d_ws, size_t ws_size,
                              hipStream_t stream) {
    const float* x    = (const float*)d_in[0];
    const int*   ei   = (const int*)d_in[1];
    const int*   batch= (const int*)d_in[2];
    const float* W1   = (const float*)d_in[3];
    const float* a1s  = (const float*)d_in[4];
    const float* a1d  = (const float*)d_in[5];
    const float* b1   = (const float*)d_in[6];
    const float* W2   = (const float*)d_in[7];
    const float* a2s  = (const float*)d_in[8];
    const float* a2d  = (const float*)d_in[9];
    const float* b2   = (const float*)d_in[10];
    const float* Wlin = (const float*)d_in[11];
    const float* blin = (const float*)d_in[12];
    float* out = (float*)d_out;
    char* ws = (char*)d_ws;
    (void)in_sizes; (void)n_in; (void)out_size; (void)ws_size;

    size_t o = 0;
    // ---- zeroed region ----
    size_t DEG  = o; o += alignup((size_t)NN * 4);          // deg, reused as cursor
    size_t PSUM = o; o += alignup((size_t)NG * 32 * 4);
    size_t PCNT = o; o += alignup((size_t)NG * 4);
    size_t GMX1 = o; o += alignup(8 * 4);
    size_t GMX2 = o; o += alignup(4);
    size_t zero_bytes = o;
    // ---- overwritten region ----
    size_t ROWP = o; o += alignup((size_t)(NN + 1) * 4);
    size_t BSUM = o; o += alignup((size_t)256 * 4);
    size_t CSR  = o; o += alignup((size_t)ETOT * 4);
    size_t H1   = o; o += alignup((size_t)NN * 64 * 4);     // reused as out2
    size_t AL1S = o; o += alignup((size_t)NN * 8 * 4);
    size_t AL1D = o; o += alignup((size_t)NN * 8 * 4);
    size_t OUT1 = o; o += alignup((size_t)NN * 64 * 4);
    size_t H2   = o; o += alignup((size_t)NN * 32 * 4);
    size_t AL2S = o; o += alignup((size_t)NN * 4);
    size_t AL2D = o; o += alignup((size_t)NN * 4);

    int*      deg    = (int*)(ws + DEG);
    float*    psum   = (float*)(ws + PSUM);
    float*    pcnt   = (float*)(ws + PCNT);
    unsigned* gmax1  = (unsigned*)(ws + GMX1);
    unsigned* gmax2  = (unsigned*)(ws + GMX2);
    int*      rowptr = (int*)(ws + ROWP);
    int*      bsum   = (int*)(ws + BSUM);
    int*      csr    = (int*)(ws + CSR);
    float*    h1     = (float*)(ws + H1);
    float*    al1s   = (float*)(ws + AL1S);
    float*    al1d   = (float*)(ws + AL1D);
    float*    out1   = (float*)(ws + OUT1);
    float*    h2     = (float*)(ws + H2);
    float*    al2s   = (float*)(ws + AL2S);
    float*    al2d   = (float*)(ws + AL2D);
    float*    out2   = h1;                      // alias: h1 dead after agg1

    hipMemsetAsync(ws, 0, zero_bytes, stream);

    gemm1<<<(NN + 15) / 16, 256, 0, stream>>>(x, W1, a1s, a1d, h1, al1s, al1d);

    const int gE = (ETOT + 255) / 256;
    const int nbScan = (NN + 255) / 256;          // 196
    hist<<<gE, 256, 0, stream>>>(ei, deg);
    scan1<<<nbScan, 256, 0, stream>>>(deg, rowptr, bsum);
    scan2<<<1, 256, 0, stream>>>(bsum, nbScan);
    scan3<<<(NN + 256) / 256, 256, 0, stream>>>(rowptr, bsum, deg);
    fillcsr<<<gE, 256, 0, stream>>>(ei, rowptr, deg, csr);

    maxal1<<<98, 256, 0, stream>>>(al1s, gmax1);

    const int gN = (NN + 3) / 4;
    agg1<<<gN, 256, 0, stream>>>(rowptr, csr, al1s, al1d, gmax1, h1, out1);

    gemm2<<<(NN + 7) / 8, 256, 0, stream>>>(out1, b1, W2, a2s, a2d, h2, al2s, al2d);

    maxal2<<<98, 256, 0, stream>>>(al2s, gmax2);

    agg2<<<gN, 256, 0, stream>>>(rowptr, csr, al2s, al2d, gmax2, h2, out2);

    pool<<<(NN + 255) / 256, 256, 0, stream>>>(out2, b2, batch, psum, pcnt);

    final_lin<<<1, 128, 0, stream>>>(psum, pcnt, Wlin, blin, out);
}

// Round 6
// 307.742 us; speedup vs baseline: 9.2030x; 1.0479x over previous
//
#include <hip/hip_runtime.h>

#define NN 50000
#define EE 800000
#define ETOT (EE + NN)     // edges + self-loops
#define NEG 0.2f
#define NG 64

__device__ __forceinline__ float lrelu(float x) { return x > 0.f ? x : NEG * x; }
__device__ __forceinline__ unsigned fenc(float f) {
    unsigned u = __float_as_uint(f);
    return (u & 0x80000000u) ? ~u : (u | 0x80000000u);
}
__device__ __forceinline__ float fdec(unsigned u) {
    return (u & 0x80000000u) ? __uint_as_float(u & 0x7fffffffu)
                             : __uint_as_float(~u);
}

// ---------- GEMM1: h1 = x @ W1 (f32); al1_s/al1_d fused ----------
// 64x64 tile, 4x4 register blocking, BK=64 two-stage
__global__ __launch_bounds__(256) void gemm1(const float* __restrict__ x,
                                             const float* __restrict__ W1,
                                             const float* __restrict__ a1s,
                                             const float* __restrict__ a1d,
                                             float* __restrict__ h1,
                                             float* __restrict__ al1s,
                                             float* __restrict__ al1d) {
    __shared__ float sx[64][132];   // pad 132: 16B-aligned rows, conflict-lite column reads
    __shared__ float sW[64][64];
    const int t = threadIdx.x;
    const int row0 = blockIdx.x * 64;
    for (int i = t * 4; i < 64 * 128; i += 256 * 4) {
        int r = i >> 7, k = i & 127;
        int gr = row0 + r;
        float4 v = make_float4(0.f, 0.f, 0.f, 0.f);
        if (gr < NN) v = *(const float4*)&x[(size_t)gr * 128 + k];
        *(float4*)&sx[r][k] = v;
    }
    float acc[4][4] = {{0.f, 0.f, 0.f, 0.f}};
    const int c4 = (t & 15) * 4;
    const int r4 = (t >> 4) * 4;
    for (int k0 = 0; k0 < 128; k0 += 64) {
        __syncthreads();
        for (int i = t * 4; i < 64 * 64; i += 256 * 4) {
            int kk = i >> 6, c = i & 63;
            *(float4*)&sW[kk][c] = *(const float4*)&W1[(size_t)(k0 + kk) * 64 + c];
        }
        __syncthreads();
#pragma unroll 8
        for (int kk = 0; kk < 64; ++kk) {
            float4 wv = *(float4*)&sW[kk][c4];
            float x0 = sx[r4 + 0][k0 + kk];
            float x1 = sx[r4 + 1][k0 + kk];
            float x2 = sx[r4 + 2][k0 + kk];
            float x3 = sx[r4 + 3][k0 + kk];
            acc[0][0] += x0 * wv.x; acc[0][1] += x0 * wv.y; acc[0][2] += x0 * wv.z; acc[0][3] += x0 * wv.w;
            acc[1][0] += x1 * wv.x; acc[1][1] += x1 * wv.y; acc[1][2] += x1 * wv.z; acc[1][3] += x1 * wv.w;
            acc[2][0] += x2 * wv.x; acc[2][1] += x2 * wv.y; acc[2][2] += x2 * wv.z; acc[2][3] += x2 * wv.w;
            acc[3][0] += x3 * wv.x; acc[3][1] += x3 * wv.y; acc[3][2] += x3 * wv.z; acc[3][3] += x3 * wv.w;
        }
    }
    const float4 asv = *(const float4*)&a1s[c4];
    const float4 adv = *(const float4*)&a1d[c4];
#pragma unroll
    for (int r = 0; r < 4; ++r) {
        int row = row0 + r4 + r;
        float ps = acc[r][0] * asv.x + acc[r][1] * asv.y + acc[r][2] * asv.z + acc[r][3] * asv.w;
        float pd = acc[r][0] * adv.x + acc[r][1] * adv.y + acc[r][2] * adv.z + acc[r][3] * adv.w;
        ps += __shfl_xor(ps, 1);     // pair covers one head (8 channels)
        pd += __shfl_xor(pd, 1);
        if (row < NN) {
            *(float4*)&h1[(size_t)row * 64 + c4] =
                make_float4(acc[r][0], acc[r][1], acc[r][2], acc[r][3]);
            if ((t & 1) == 0) {
                int h = (t & 15) >> 1;
                al1s[row * 8 + h] = ps;
                al1d[row * 8 + h] = pd;
            }
        }
    }
}

// ---------- CSR build ----------
__global__ __launch_bounds__(256) void hist(const int* __restrict__ ei,
                                            int* __restrict__ deg) {
    int e = blockIdx.x * 256 + threadIdx.x;
    if (e >= ETOT) return;
    int d = (e < EE) ? ei[EE + e] : e - EE;
    atomicAdd(&deg[d], 1);
}

__global__ __launch_bounds__(256) void scan1(const int* __restrict__ deg,
                                             int* __restrict__ rowptr,
                                             int* __restrict__ bsum) {
    __shared__ int s[256];
    int t = threadIdx.x;
    int i = blockIdx.x * 256 + t;
    int v = (i < NN) ? deg[i] : 0;
    s[t] = v;
    __syncthreads();
    for (int off = 1; off < 256; off <<= 1) {
        int u = (t >= off) ? s[t - off] : 0;
        __syncthreads();
        s[t] += u;
        __syncthreads();
    }
    if (i < NN) rowptr[i] = s[t] - v;
    if (t == 255) bsum[blockIdx.x] = s[255];
}

__global__ __launch_bounds__(256) void scan2(int* __restrict__ bsum, int nb) {
    __shared__ int s[256];
    int t = threadIdx.x;
    int v = (t < nb) ? bsum[t] : 0;
    s[t] = v;
    __syncthreads();
    for (int off = 1; off < 256; off <<= 1) {
        int u = (t >= off) ? s[t - off] : 0;
        __syncthreads();
        s[t] += u;
        __syncthreads();
    }
    if (t < nb) bsum[t] = s[t] - v;
}

__global__ __launch_bounds__(256) void scan3(int* __restrict__ rowptr,
                                             const int* __restrict__ bsum,
                                             int* __restrict__ deg) {
    int i = blockIdx.x * 256 + threadIdx.x;
    if (i < NN) {
        rowptr[i] += bsum[i >> 8];
        deg[i] = 0;
    }
    if (i == NN) rowptr[NN] = ETOT;
}

__global__ __launch_bounds__(256) void fillcsr(const int* __restrict__ ei,
                                               const int* __restrict__ rowptr,
                                               int* __restrict__ cursor,
                                               int* __restrict__ csr) {
    int e = blockIdx.x * 256 + threadIdx.x;
    if (e >= ETOT) return;
    int s, d;
    if (e < EE) { s = ei[e]; d = ei[EE + e]; } else { s = d = e - EE; }
    int pos = atomicAdd(&cursor[d], 1);
    csr[rowptr[d] + pos] = s;
}

// ---------- global per-head max of al1s ----------
__global__ __launch_bounds__(256) void maxal1(const float* __restrict__ al1s,
                                              unsigned* __restrict__ gmax1) {
    const int t = blockIdx.x * 256 + threadIdx.x;
    const int h = t & 7;
    float m = -1e30f;
    for (int i = t; i < NN * 8; i += 98 * 256) m = fmaxf(m, al1s[i]);
    m = fmaxf(m, __shfl_xor(m, 8));
    m = fmaxf(m, __shfl_xor(m, 16));
    m = fmaxf(m, __shfl_xor(m, 32));
    if ((threadIdx.x & 63) < 8) atomicMax(&gmax1[h], fenc(m));
}

__global__ __launch_bounds__(256) void maxal2(const float* __restrict__ al2s,
                                              unsigned* __restrict__ gmax2) {
    const int t = blockIdx.x * 256 + threadIdx.x;
    float m = -1e30f;
    for (int i = t; i < NN; i += 98 * 256) m = fmaxf(m, al2s[i]);
#pragma unroll
    for (int off = 32; off; off >>= 1) m = fmaxf(m, __shfl_xor(m, off));
    if ((threadIdx.x & 63) == 0) atomicMax(gmax2, fenc(m));
}

// ---------- fused: layer-1 softmax-aggregate + bias + elu + GEMM2 + al2 ----------
// one wave per dst node (grid-stride); W2 kept in 32 regs/lane
__global__ __launch_bounds__(256) void agg1f(const int* __restrict__ rowptr,
                                             const int* __restrict__ csr,
                                             const float* __restrict__ al1s,
                                             const float* __restrict__ al1d,
                                             const unsigned* __restrict__ gmax1,
                                             const float* __restrict__ h1,
                                             const float* __restrict__ b1,
                                             const float* __restrict__ W2,
                                             const float* __restrict__ a2s,
                                             const float* __restrict__ a2d,
                                             float* __restrict__ h2,
                                             float* __restrict__ al2s,
                                             float* __restrict__ al2d) {
    const int lane = threadIdx.x & 63;
    const int wid  = blockIdx.x * 4 + (threadIdx.x >> 6);
    const int NW   = gridDim.x * 4;
    const int c = lane & 31, halfk = lane >> 5;
    float w2r[32];
#pragma unroll
    for (int j = 0; j < 32; ++j) w2r[j] = W2[(size_t)(halfk * 32 + j) * 32 + c];
    const float a2sc = a2s[c], a2dc = a2d[c];
    const float b1l  = b1[lane];
    const int hh = lane >> 3;
    const float M0 = fdec(gmax1[hh]);

    for (int d = wid; d < NN; d += NW) {
        const int beg = rowptr[d], end = rowptr[d + 1];
        const float ald = al1d[d * 8 + hh];
        const float M = lrelu(M0 + ald);     // valid upper bound on this node's logits
        float den = 0.f, acc = 0.f;
        for (int base = beg; base < end; base += 64) {
            int cnt = min(64, end - base);
            int myedge = (base + lane < end) ? csr[base + lane] : 0;
            int j = 0;
            for (; j + 3 < cnt; j += 4) {
                int s0 = __shfl(myedge, j);
                int s1 = __shfl(myedge, j + 1);
                int s2 = __shfl(myedge, j + 2);
                int s3 = __shfl(myedge, j + 3);
                float l0 = al1s[s0 * 8 + hh], l1 = al1s[s1 * 8 + hh];
                float l2 = al1s[s2 * 8 + hh], l3 = al1s[s3 * 8 + hh];
                float g0 = h1[(size_t)s0 * 64 + lane];
                float g1 = h1[(size_t)s1 * 64 + lane];
                float g2 = h1[(size_t)s2 * 64 + lane];
                float g3 = h1[(size_t)s3 * 64 + lane];
                float a0 = __expf(lrelu(l0 + ald) - M);
                float a1 = __expf(lrelu(l1 + ald) - M);
                float a2 = __expf(lrelu(l2 + ald) - M);
                float a3 = __expf(lrelu(l3 + ald) - M);
                den += (a0 + a1) + (a2 + a3);
                acc += a0 * g0; acc += a1 * g1; acc += a2 * g2; acc += a3 * g3;
            }
            for (; j < cnt; ++j) {
                int s0 = __shfl(myedge, j);
                float a0 = __expf(lrelu(al1s[s0 * 8 + hh] + ald) - M);
                den += a0;
                acc += a0 * h1[(size_t)s0 * 64 + lane];
            }
        }
        float v = acc / (den + 1e-16f) + b1l;
        v = v > 0.f ? v : (__expf(v) - 1.f);   // elu
        // h2 row: 32-step shfl dot (each half covers 32 k's)
        float acc2 = 0.f;
        const int kb = lane & 32;
#pragma unroll
        for (int j = 0; j < 32; ++j) acc2 += __shfl(v, kb + j) * w2r[j];
        acc2 += __shfl_xor(acc2, 32);
        float ps = acc2 * a2sc, pd = acc2 * a2dc;
#pragma unroll
        for (int off = 1; off < 32; off <<= 1) {
            ps += __shfl_xor(ps, off);
            pd += __shfl_xor(pd, off);
        }
        if (lane == 0) { al2s[d] = ps; al2d[d] = pd; }
        if (halfk == 0) h2[(size_t)d * 32 + c] = acc2;
    }
}

// ---------- layer-2 softmax + aggregate: R3-exact known-good version ----------
__global__ __launch_bounds__(256) void agg2(const int* __restrict__ rowptr,
                                            const int* __restrict__ csr,
                                            const float* __restrict__ al2s,
                                            const float* __restrict__ al2d,
                                            const unsigned* __restrict__ gmax2,
                                            const float* __restrict__ h2,
                                            float* __restrict__ out2) {
    const int lane = threadIdx.x & 63;
    const int d = blockIdx.x * 4 + (threadIdx.x >> 6);
    if (d >= NN) return;
    const int beg = rowptr[d], end = rowptr[d + 1];
    const float ald = al2d[d];
    const float M = lrelu(fdec(gmax2[0]) + ald);
    const int sub = lane >> 5, c = lane & 31;    // 2 edges x 32 channels
    float den = 0.f, acc = 0.f;
    for (int i = beg + sub; i < end; i += 2) {
        int s = csr[i];
        float a = __expf(lrelu(al2s[s] + ald) - M);
        den += a;
        acc += a * h2[(size_t)s * 32 + c];
    }
    den += __shfl_xor(den, 32);
    acc += __shfl_xor(acc, 32);
    if (sub == 0) out2[(size_t)d * 32 + c] = acc / (den + 1e-16f);
}

// ---------- pooling (batch sorted -> block-local LDS accumulation) ----------
__global__ __launch_bounds__(256) void pool(const float* __restrict__ out2,
                                            const float* __restrict__ b2,
                                            const int* __restrict__ batch,
                                            float* __restrict__ psum,
                                            float* __restrict__ pcnt) {
    __shared__ float sacc[8][32];
    __shared__ float scnt[8];
    const int t = threadIdx.x;
    const int c = t & 31, sl = t >> 5;
    const int n0 = blockIdx.x * 256;
    const int g0 = batch[n0 < NN ? n0 : NN - 1];
    float acc = 0.f, cnt = 0.f;
    for (int k = 0; k < 32; ++k) {
        int n = n0 + sl + 8 * k;
        if (n < NN) {
            float v = out2[(size_t)n * 32 + c] + b2[c];
            int g = batch[n];
            if (g == g0) {
                acc += v;
                if (c == 0) cnt += 1.f;
            } else {
                atomicAdd(&psum[g * 32 + c], v);
                if (c == 0) atomicAdd(&pcnt[g], 1.f);
            }
        }
    }
    sacc[sl][c] = acc;
    if (c == 0) scnt[sl] = cnt;
    __syncthreads();
    if (t < 32) {
        float s = 0.f;
        for (int j = 0; j < 8; ++j) s += sacc[j][t];
        atomicAdd(&psum[g0 * 32 + t], s);
        if (t == 0) {
            float sc = 0.f;
            for (int j = 0; j < 8; ++j) sc += scnt[j];
            atomicAdd(&pcnt[g0], sc);
        }
    }
}

__global__ __launch_bounds__(128) void final_lin(const float* __restrict__ psum,
                                                 const float* __restrict__ pcnt,
                                                 const float* __restrict__ Wlin,
                                                 const float* __restrict__ blin,
                                                 float* __restrict__ out) {
    int t = threadIdx.x;
    if (t >= NG * 2) return;
    int g = t >> 1, j = t & 1;
    float cnt = fmaxf(pcnt[g], 1.0f);
    float acc = blin[j];
    for (int c = 0; c < 32; ++c) acc += (psum[g * 32 + c] / cnt) * Wlin[c * 2 + j];
    out[g * 2 + j] = acc;
}

// ---------- launch ----------
static inline size_t alignup(size_t x) { return (x + 255) & ~(size_t)255; }

extern "C" void kernel_launch(void* const* d_in, const int* in_sizes, int n_in,
                              void* d_out, int out_size, void* d_ws, size_t ws_size,
                              hipStream_t stream) {
    const float* x    = (const float*)d_in[0];
    const int*   ei   = (const int*)d_in[1];
    const int*   batch= (const int*)d_in[2];
    const float* W1   = (const float*)d_in[3];
    const float* a1s  = (const float*)d_in[4];
    const float* a1d  = (const float*)d_in[5];
    const float* b1   = (const float*)d_in[6];
    const float* W2   = (const float*)d_in[7];
    const float* a2s  = (const float*)d_in[8];
    const float* a2d  = (const float*)d_in[9];
    const float* b2   = (const float*)d_in[10];
    const float* Wlin = (const float*)d_in[11];
    const float* blin = (const float*)d_in[12];
    float* out = (float*)d_out;
    char* ws = (char*)d_ws;
    (void)in_sizes; (void)n_in; (void)out_size; (void)ws_size;

    size_t o = 0;
    // ---- zeroed region ----
    size_t DEG  = o; o += alignup((size_t)NN * 4);          // deg, reused as cursor
    size_t PSUM = o; o += alignup((size_t)NG * 32 * 4);
    size_t PCNT = o; o += alignup((size_t)NG * 4);
    size_t GMX1 = o; o += alignup(8 * 4);
    size_t GMX2 = o; o += alignup(4);
    size_t zero_bytes = o;
    // ---- overwritten region ----
    size_t ROWP = o; o += alignup((size_t)(NN + 1) * 4);
    size_t BSUM = o; o += alignup((size_t)256 * 4);
    size_t CSR  = o; o += alignup((size_t)ETOT * 4 + 256);  // +slack for benign OOB lane reads
    size_t H1   = o; o += alignup((size_t)NN * 64 * 4);
    size_t AL1S = o; o += alignup((size_t)NN * 8 * 4);
    size_t AL1D = o; o += alignup((size_t)NN * 8 * 4);
    size_t H2   = o; o += alignup((size_t)NN * 32 * 4);
    size_t AL2S = o; o += alignup((size_t)NN * 4);
    size_t AL2D = o; o += alignup((size_t)NN * 4);
    size_t OUT2 = o; o += alignup((size_t)NN * 32 * 4);

    int*      deg    = (int*)(ws + DEG);
    float*    psum   = (float*)(ws + PSUM);
    float*    pcnt   = (float*)(ws + PCNT);
    unsigned* gmax1  = (unsigned*)(ws + GMX1);
    unsigned* gmax2  = (unsigned*)(ws + GMX2);
    int*      rowptr = (int*)(ws + ROWP);
    int*      bsum   = (int*)(ws + BSUM);
    int*      csr    = (int*)(ws + CSR);
    float*    h1     = (float*)(ws + H1);
    float*    al1s_  = (float*)(ws + AL1S);
    float*    al1d_  = (float*)(ws + AL1D);
    float*    h2     = (float*)(ws + H2);
    float*    al2s   = (float*)(ws + AL2S);
    float*    al2d   = (float*)(ws + AL2D);
    float*    out2   = (float*)(ws + OUT2);

    hipMemsetAsync(ws, 0, zero_bytes, stream);

    gemm1<<<(NN + 63) / 64, 256, 0, stream>>>(x, W1, a1s, a1d, h1, al1s_, al1d_);

    const int gE = (ETOT + 255) / 256;
    const int nbScan = (NN + 255) / 256;          // 196
    hist<<<gE, 256, 0, stream>>>(ei, deg);
    scan1<<<nbScan, 256, 0, stream>>>(deg, rowptr, bsum);
    scan2<<<1, 256, 0, stream>>>(bsum, nbScan);
    scan3<<<(NN + 256) / 256, 256, 0, stream>>>(rowptr, bsum, deg);
    fillcsr<<<gE, 256, 0, stream>>>(ei, rowptr, deg, csr);

    maxal1<<<98, 256, 0, stream>>>(al1s_, gmax1);

    agg1f<<<2048, 256, 0, stream>>>(rowptr, csr, al1s_, al1d_, gmax1, h1,
                                    b1, W2, a2s, a2d, h2, al2s, al2d);

    maxal2<<<98, 256, 0, stream>>>(al2s, gmax2);

    const int gN = (NN + 3) / 4;
    agg2<<<gN, 256, 0, stream>>>(rowptr, csr, al2s, al2d, gmax2, h2, out2);

    pool<<<(NN + 255) / 256, 256, 0, stream>>>(out2, b2, batch, psum, pcnt);

    final_lin<<<1, 128, 0, stream>>>(psum, pcnt, Wlin, blin, out);
}

// Round 7
// 296.859 us; speedup vs baseline: 9.5404x; 1.0367x over previous
//
#include <hip/hip_runtime.h>

#define NN 50000
#define EE 800000
#define ETOT (EE + NN)     // edges + self-loops
#define NEG 0.2f
#define NG 64

__device__ __forceinline__ float lrelu(float x) { return x > 0.f ? x : NEG * x; }
__device__ __forceinline__ unsigned fenc(float f) {
    unsigned u = __float_as_uint(f);
    return (u & 0x80000000u) ? ~u : (u | 0x80000000u);
}
__device__ __forceinline__ float fdec(unsigned u) {
    return (u & 0x80000000u) ? __uint_as_float(u & 0x7fffffffu)
                             : __uint_as_float(~u);
}

// ---------- GEMM1: h1 = x @ W1 (f32); al1_s/al1_d fused; global head-max fused ----------
// 64x64 tile, 4x4 register blocking, BK=64 two-stage, float4 LDS reads
__global__ __launch_bounds__(256) void gemm1(const float* __restrict__ x,
                                             const float* __restrict__ W1,
                                             const float* __restrict__ a1s,
                                             const float* __restrict__ a1d,
                                             float* __restrict__ h1,
                                             float* __restrict__ al1s,
                                             float* __restrict__ al1d,
                                             unsigned* __restrict__ gmax1) {
    __shared__ float sx[64][132];   // row stride 528B (16B-aligned)
    __shared__ float sW[64][64];
    const int t = threadIdx.x;
    const int row0 = blockIdx.x * 64;
    for (int i = t * 4; i < 64 * 128; i += 256 * 4) {
        int r = i >> 7, k = i & 127;
        int gr = row0 + r;
        float4 v = make_float4(0.f, 0.f, 0.f, 0.f);
        if (gr < NN) v = *(const float4*)&x[(size_t)gr * 128 + k];
        *(float4*)&sx[r][k] = v;
    }
    float acc[4][4] = {{0.f, 0.f, 0.f, 0.f}};
    const int c4 = (t & 15) * 4;
    const int r4 = (t >> 4) * 4;
    for (int k0 = 0; k0 < 128; k0 += 64) {
        __syncthreads();
        for (int i = t * 4; i < 64 * 64; i += 256 * 4) {
            int kk = i >> 6, c = i & 63;
            *(float4*)&sW[kk][c] = *(const float4*)&W1[(size_t)(k0 + kk) * 64 + c];
        }
        __syncthreads();
#pragma unroll 4
        for (int kk = 0; kk < 64; kk += 4) {
            float4 wv0 = *(float4*)&sW[kk + 0][c4];
            float4 wv1 = *(float4*)&sW[kk + 1][c4];
            float4 wv2 = *(float4*)&sW[kk + 2][c4];
            float4 wv3 = *(float4*)&sW[kk + 3][c4];
#pragma unroll
            for (int r = 0; r < 4; ++r) {
                float4 xv = *(const float4*)&sx[r4 + r][k0 + kk];
                acc[r][0] += xv.x * wv0.x; acc[r][1] += xv.x * wv0.y; acc[r][2] += xv.x * wv0.z; acc[r][3] += xv.x * wv0.w;
                acc[r][0] += xv.y * wv1.x; acc[r][1] += xv.y * wv1.y; acc[r][2] += xv.y * wv1.z; acc[r][3] += xv.y * wv1.w;
                acc[r][0] += xv.z * wv2.x; acc[r][1] += xv.z * wv2.y; acc[r][2] += xv.z * wv2.z; acc[r][3] += xv.z * wv2.w;
                acc[r][0] += xv.w * wv3.x; acc[r][1] += xv.w * wv3.y; acc[r][2] += xv.w * wv3.z; acc[r][3] += xv.w * wv3.w;
            }
        }
    }
    const float4 asv = *(const float4*)&a1s[c4];
    const float4 adv = *(const float4*)&a1d[c4];
    float pmax = -1e30f;
#pragma unroll
    for (int r = 0; r < 4; ++r) {
        int row = row0 + r4 + r;
        float ps = acc[r][0] * asv.x + acc[r][1] * asv.y + acc[r][2] * asv.z + acc[r][3] * asv.w;
        float pd = acc[r][0] * adv.x + acc[r][1] * adv.y + acc[r][2] * adv.z + acc[r][3] * adv.w;
        ps += __shfl_xor(ps, 1);     // pair covers one head (8 channels)
        pd += __shfl_xor(pd, 1);
        pmax = fmaxf(pmax, ps);      // padding rows give ps=0: harmless upper bound
        if (row < NN) {
            *(float4*)&h1[(size_t)row * 64 + c4] =
                make_float4(acc[r][0], acc[r][1], acc[r][2], acc[r][3]);
            if ((t & 1) == 0) {
                int h = (t & 15) >> 1;
                al1s[row * 8 + h] = ps;
                al1d[row * 8 + h] = pd;
            }
        }
    }
    // fused per-head global max (upper bound): reduce over this wave's 16 rows
    pmax = fmaxf(pmax, __shfl_xor(pmax, 16));
    pmax = fmaxf(pmax, __shfl_xor(pmax, 32));
    if ((t & 49) == 0)   // 8 lanes/wave: bits 0,4,5 clear -> t&15 in {0,2,..,14}
        atomicMax(&gmax1[(t & 15) >> 1], fenc(pmax));
}

// ---------- CSR build ----------
__global__ __launch_bounds__(256) void hist(const int* __restrict__ ei,
                                            int* __restrict__ deg) {
    int e = blockIdx.x * 256 + threadIdx.x;
    if (e >= ETOT) return;
    int d = (e < EE) ? ei[EE + e] : e - EE;
    atomicAdd(&deg[d], 1);
}

__global__ __launch_bounds__(256) void scan1(const int* __restrict__ deg,
                                             int* __restrict__ rowptr,
                                             int* __restrict__ bsum) {
    __shared__ int s[256];
    int t = threadIdx.x;
    int i = blockIdx.x * 256 + t;
    int v = (i < NN) ? deg[i] : 0;
    s[t] = v;
    __syncthreads();
    for (int off = 1; off < 256; off <<= 1) {
        int u = (t >= off) ? s[t - off] : 0;
        __syncthreads();
        s[t] += u;
        __syncthreads();
    }
    if (i < NN) rowptr[i] = s[t] - v;
    if (t == 255) bsum[blockIdx.x] = s[255];
}

// merged scan2+scan3: each block computes its own bsum-prefix, adds it,
// finalizes rowptr[NN], zeroes deg for reuse as cursor
__global__ __launch_bounds__(256) void scan23(int* __restrict__ rowptr,
                                              const int* __restrict__ bsum,
                                              int* __restrict__ deg) {
    __shared__ int soff;
    const int B = blockIdx.x;
    if (threadIdx.x < 64) {
        int sacc = 0;
        for (int idx = threadIdx.x; idx < B; idx += 64) sacc += bsum[idx];
#pragma unroll
        for (int off = 1; off < 64; off <<= 1) sacc += __shfl_xor(sacc, off);
        if (threadIdx.x == 0) soff = sacc;
    }
    __syncthreads();
    int i = B * 256 + threadIdx.x;
    if (i < NN) {
        rowptr[i] += soff;
        deg[i] = 0;
    }
    if (i == NN) rowptr[NN] = ETOT;
}

__global__ __launch_bounds__(256) void fillcsr(const int* __restrict__ ei,
                                               const int* __restrict__ rowptr,
                                               int* __restrict__ cursor,
                                               int* __restrict__ csr) {
    int e = blockIdx.x * 256 + threadIdx.x;
    if (e >= ETOT) return;
    int s, d;
    if (e < EE) { s = ei[e]; d = ei[EE + e]; } else { s = d = e - EE; }
    int pos = atomicAdd(&cursor[d], 1);
    csr[rowptr[d] + pos] = s;
}

// ---------- global max of al2s (1 value) ----------
__global__ __launch_bounds__(256) void maxal2(const float* __restrict__ al2s,
                                              unsigned* __restrict__ gmax2) {
    const int t = blockIdx.x * 256 + threadIdx.x;
    float m = -1e30f;
    for (int i = t; i < NN; i += 98 * 256) m = fmaxf(m, al2s[i]);
#pragma unroll
    for (int off = 32; off; off >>= 1) m = fmaxf(m, __shfl_xor(m, off));
    if ((threadIdx.x & 63) == 0) atomicMax(gmax2, fenc(m));
}

// ---------- fused: layer-1 softmax-aggregate + bias + elu + GEMM2 + al2 ----------
// one wave per dst node (grid-stride); 4 edge-groups x 16 chan-quads; float4 gathers
__global__ __launch_bounds__(256) void agg1f(const int* __restrict__ rowptr,
                                             const int* __restrict__ csr,
                                             const float* __restrict__ al1s,
                                             const float* __restrict__ al1d,
                                             const unsigned* __restrict__ gmax1,
                                             const float* __restrict__ h1,
                                             const float* __restrict__ b1,
                                             const float* __restrict__ W2,
                                             const float* __restrict__ a2s,
                                             const float* __restrict__ a2d,
                                             float* __restrict__ h2,
                                             float* __restrict__ al2s,
                                             float* __restrict__ al2d) {
    const int lane = threadIdx.x & 63;
    const int wid  = blockIdx.x * 4 + (threadIdx.x >> 6);
    const int NW   = gridDim.x * 4;
    const int u  = lane & 15;     // channel-quad: channels u*4 .. u*4+3
    const int g  = lane >> 4;     // edge group 0..3
    const int hh = u >> 1;        // head of this channel-quad
    const int c = lane & 31, halfk = lane >> 5;   // epilogue layout (R6)
    float w2r[32];
#pragma unroll
    for (int j = 0; j < 32; ++j) w2r[j] = W2[(size_t)(halfk * 32 + j) * 32 + c];
    const float a2sc = a2s[c], a2dc = a2d[c];
    const float4 b14 = *(const float4*)&b1[u * 4];
    const float M0 = fdec(gmax1[hh]);

    for (int d = wid; d < NN; d += NW) {
        const int beg = rowptr[d], end = rowptr[d + 1];
        const float ald = al1d[d * 8 + hh];
        const float M = lrelu(M0 + ald);     // upper bound on this node/head's logits
        float den = 0.f;
        float4 a4 = make_float4(0.f, 0.f, 0.f, 0.f);
        for (int base = beg; base < end; base += 64) {
            int cnt = min(64, end - base);
            int myedge = (base + lane < end) ? csr[base + lane] : 0;
            for (int tt = 0; 4 * tt < cnt; ++tt) {
                int j = 4 * tt + g;
                bool valid = j < cnt;
                int jj = valid ? j : cnt - 1;
                int s = __shfl(myedge, jj);
                float al = al1s[s * 8 + hh];
                float4 hv = *(const float4*)&h1[(size_t)s * 64 + u * 4];
                float a = valid ? __expf(lrelu(al + ald) - M) : 0.f;
                den += a;
                a4.x += a * hv.x; a4.y += a * hv.y;
                a4.z += a * hv.z; a4.w += a * hv.w;
            }
        }
        // reduce over the 4 edge groups (lane bits 4,5)
        den += __shfl_xor(den, 16); den += __shfl_xor(den, 32);
        a4.x += __shfl_xor(a4.x, 16); a4.x += __shfl_xor(a4.x, 32);
        a4.y += __shfl_xor(a4.y, 16); a4.y += __shfl_xor(a4.y, 32);
        a4.z += __shfl_xor(a4.z, 16); a4.z += __shfl_xor(a4.z, 32);
        a4.w += __shfl_xor(a4.w, 16); a4.w += __shfl_xor(a4.w, 32);
        const float inv = 1.f / (den + 1e-16f);
        float4 v4;
        v4.x = a4.x * inv + b14.x; v4.y = a4.y * inv + b14.y;
        v4.z = a4.z * inv + b14.z; v4.w = a4.w * inv + b14.w;
        v4.x = v4.x > 0.f ? v4.x : (__expf(v4.x) - 1.f);
        v4.y = v4.y > 0.f ? v4.y : (__expf(v4.y) - 1.f);
        v4.z = v4.z > 0.f ? v4.z : (__expf(v4.z) - 1.f);
        v4.w = v4.w > 0.f ? v4.w : (__expf(v4.w) - 1.f);
        // transpose: lane picks up scalar channel `lane`
        float t0 = __shfl(v4.x, lane >> 2);
        float t1 = __shfl(v4.y, lane >> 2);
        float t2 = __shfl(v4.z, lane >> 2);
        float t3 = __shfl(v4.w, lane >> 2);
        int q = lane & 3;
        float v = (q == 0) ? t0 : (q == 1) ? t1 : (q == 2) ? t2 : t3;
        // h2 row: 32-step shfl dot (R6-proven epilogue)
        float acc2 = 0.f;
        const int kb = lane & 32;
#pragma unroll
        for (int j = 0; j < 32; ++j) acc2 += __shfl(v, kb + j) * w2r[j];
        acc2 += __shfl_xor(acc2, 32);
        float ps = acc2 * a2sc, pd = acc2 * a2dc;
#pragma unroll
        for (int off = 1; off < 32; off <<= 1) {
            ps += __shfl_xor(ps, off);
            pd += __shfl_xor(pd, off);
        }
        if (lane == 0) { al2s[d] = ps; al2d[d] = pd; }
        if (halfk == 0) h2[(size_t)d * 32 + c] = acc2;
    }
}

// ---------- layer-2 softmax + aggregate: 8 edge-groups x 8 chan-quads, float4 ----------
__global__ __launch_bounds__(256) void agg2(const int* __restrict__ rowptr,
                                            const int* __restrict__ csr,
                                            const float* __restrict__ al2s,
                                            const float* __restrict__ al2d,
                                            const unsigned* __restrict__ gmax2,
                                            const float* __restrict__ h2,
                                            float* __restrict__ out2) {
    const int lane = threadIdx.x & 63;
    const int d = blockIdx.x * 4 + (threadIdx.x >> 6);
    if (d >= NN) return;
    const int u = lane & 7;      // channel-quad
    const int g = lane >> 3;     // edge group 0..7
    const int beg = rowptr[d], end = rowptr[d + 1];
    const float ald = al2d[d];
    const float M = lrelu(fdec(gmax2[0]) + ald);
    float den = 0.f;
    float4 a4 = make_float4(0.f, 0.f, 0.f, 0.f);
    for (int base = beg; base < end; base += 64) {
        int cnt = min(64, end - base);
        int myedge = (base + lane < end) ? csr[base + lane] : 0;
        for (int tt = 0; 8 * tt < cnt; ++tt) {
            int j = 8 * tt + g;
            bool valid = j < cnt;
            int jj = valid ? j : cnt - 1;
            int s = __shfl(myedge, jj);
            float al = al2s[s];
            float4 hv = *(const float4*)&h2[(size_t)s * 32 + u * 4];
            float a = valid ? __expf(lrelu(al + ald) - M) : 0.f;
            den += a;
            a4.x += a * hv.x; a4.y += a * hv.y;
            a4.z += a * hv.z; a4.w += a * hv.w;
        }
    }
    // reduce over the 8 edge groups (lane bits 3,4,5)
    den += __shfl_xor(den, 8); den += __shfl_xor(den, 16); den += __shfl_xor(den, 32);
    a4.x += __shfl_xor(a4.x, 8); a4.x += __shfl_xor(a4.x, 16); a4.x += __shfl_xor(a4.x, 32);
    a4.y += __shfl_xor(a4.y, 8); a4.y += __shfl_xor(a4.y, 16); a4.y += __shfl_xor(a4.y, 32);
    a4.z += __shfl_xor(a4.z, 8); a4.z += __shfl_xor(a4.z, 16); a4.z += __shfl_xor(a4.z, 32);
    a4.w += __shfl_xor(a4.w, 8); a4.w += __shfl_xor(a4.w, 16); a4.w += __shfl_xor(a4.w, 32);
    if (g == 0) {
        const float inv = 1.f / (den + 1e-16f);
        *(float4*)&out2[(size_t)d * 32 + u * 4] =
            make_float4(a4.x * inv, a4.y * inv, a4.z * inv, a4.w * inv);
    }
}

// ---------- pooling (batch sorted -> block-local LDS accumulation) ----------
__global__ __launch_bounds__(256) void pool(const float* __restrict__ out2,
                                            const float* __restrict__ b2,
                                            const int* __restrict__ batch,
                                            float* __restrict__ psum,
                                            float* __restrict__ pcnt) {
    __shared__ float sacc[8][32];
    __shared__ float scnt[8];
    const int t = threadIdx.x;
    const int c = t & 31, sl = t >> 5;
    const int n0 = blockIdx.x * 256;
    const int g0 = batch[n0 < NN ? n0 : NN - 1];
    float acc = 0.f, cnt = 0.f;
    for (int k = 0; k < 32; ++k) {
        int n = n0 + sl + 8 * k;
        if (n < NN) {
            float v = out2[(size_t)n * 32 + c] + b2[c];
            int g = batch[n];
            if (g == g0) {
                acc += v;
                if (c == 0) cnt += 1.f;
            } else {
                atomicAdd(&psum[g * 32 + c], v);
                if (c == 0) atomicAdd(&pcnt[g], 1.f);
            }
        }
    }
    sacc[sl][c] = acc;
    if (c == 0) scnt[sl] = cnt;
    __syncthreads();
    if (t < 32) {
        float s = 0.f;
        for (int j = 0; j < 8; ++j) s += sacc[j][t];
        atomicAdd(&psum[g0 * 32 + t], s);
        if (t == 0) {
            float sc = 0.f;
            for (int j = 0; j < 8; ++j) sc += scnt[j];
            atomicAdd(&pcnt[g0], sc);
        }
    }
}

__global__ __launch_bounds__(128) void final_lin(const float* __restrict__ psum,
                                                 const float* __restrict__ pcnt,
                                                 const float* __restrict__ Wlin,
                                                 const float* __restrict__ blin,
                                                 float* __restrict__ out) {
    int t = threadIdx.x;
    if (t >= NG * 2) return;
    int g = t >> 1, j = t & 1;
    float cnt = fmaxf(pcnt[g], 1.0f);
    float acc = blin[j];
    for (int c = 0; c < 32; ++c) acc += (psum[g * 32 + c] / cnt) * Wlin[c * 2 + j];
    out[g * 2 + j] = acc;
}

// ---------- launch ----------
static inline size_t alignup(size_t x) { return (x + 255) & ~(size_t)255; }

extern "C" void kernel_launch(void* const* d_in, const int* in_sizes, int n_in,
                              void* d_out, int out_size, void* d_ws, size_t ws_size,
                              hipStream_t stream) {
    const float* x    = (const float*)d_in[0];
    const int*   ei   = (const int*)d_in[1];
    const int*   batch= (const int*)d_in[2];
    const float* W1   = (const float*)d_in[3];
    const float* a1s  = (const float*)d_in[4];
    const float* a1d  = (const float*)d_in[5];
    const float* b1   = (const float*)d_in[6];
    const float* W2   = (const float*)d_in[7];
    const float* a2s  = (const float*)d_in[8];
    const float* a2d  = (const float*)d_in[9];
    const float* b2   = (const float*)d_in[10];
    const float* Wlin = (const float*)d_in[11];
    const float* blin = (const float*)d_in[12];
    float* out = (float*)d_out;
    char* ws = (char*)d_ws;
    (void)in_sizes; (void)n_in; (void)out_size; (void)ws_size;

    size_t o = 0;
    // ---- zeroed region ----
    size_t DEG  = o; o += alignup((size_t)NN * 4);          // deg, reused as cursor
    size_t PSUM = o; o += alignup((size_t)NG * 32 * 4);
    size_t PCNT = o; o += alignup((size_t)NG * 4);
    size_t GMX1 = o; o += alignup(8 * 4);
    size_t GMX2 = o; o += alignup(4);
    size_t zero_bytes = o;
    // ---- overwritten region ----
    size_t ROWP = o; o += alignup((size_t)(NN + 1) * 4);
    size_t BSUM = o; o += alignup((size_t)256 * 4);
    size_t CSR  = o; o += alignup((size_t)ETOT * 4 + 256);  // +slack for benign OOB lane reads
    size_t H1   = o; o += alignup((size_t)NN * 64 * 4);
    size_t AL1S = o; o += alignup((size_t)NN * 8 * 4);
    size_t AL1D = o; o += alignup((size_t)NN * 8 * 4);
    size_t H2   = o; o += alignup((size_t)NN * 32 * 4);
    size_t AL2S = o; o += alignup((size_t)NN * 4);
    size_t AL2D = o; o += alignup((size_t)NN * 4);
    size_t OUT2 = o; o += alignup((size_t)NN * 32 * 4);

    int*      deg    = (int*)(ws + DEG);
    float*    psum   = (float*)(ws + PSUM);
    float*    pcnt   = (float*)(ws + PCNT);
    unsigned* gmax1  = (unsigned*)(ws + GMX1);
    unsigned* gmax2  = (unsigned*)(ws + GMX2);
    int*      rowptr = (int*)(ws + ROWP);
    int*      bsum   = (int*)(ws + BSUM);
    int*      csr    = (int*)(ws + CSR);
    float*    h1     = (float*)(ws + H1);
    float*    al1s_  = (float*)(ws + AL1S);
    float*    al1d_  = (float*)(ws + AL1D);
    float*    h2     = (float*)(ws + H2);
    float*    al2s   = (float*)(ws + AL2S);
    float*    al2d   = (float*)(ws + AL2D);
    float*    out2   = (float*)(ws + OUT2);

    hipMemsetAsync(ws, 0, zero_bytes, stream);

    gemm1<<<(NN + 63) / 64, 256, 0, stream>>>(x, W1, a1s, a1d, h1, al1s_, al1d_, gmax1);

    const int gE = (ETOT + 255) / 256;
    const int nbScan = (NN + 255) / 256;          // 196
    hist<<<gE, 256, 0, stream>>>(ei, deg);
    scan1<<<nbScan, 256, 0, stream>>>(deg, rowptr, bsum);
    scan23<<<(NN + 256) / 256, 256, 0, stream>>>(rowptr, bsum, deg);
    fillcsr<<<gE, 256, 0, stream>>>(ei, rowptr, deg, csr);

    agg1f<<<2048, 256, 0, stream>>>(rowptr, csr, al1s_, al1d_, gmax1, h1,
                                    b1, W2, a2s, a2d, h2, al2s, al2d);

    maxal2<<<98, 256, 0, stream>>>(al2s, gmax2);

    const int gN = (NN + 3) / 4;
    agg2<<<gN, 256, 0, stream>>>(rowptr, csr, al2s, al2d, gmax2, h2, out2);

    pool<<<(NN + 255) / 256, 256, 0, stream>>>(out2, b2, batch, psum, pcnt);

    final_lin<<<1, 128, 0, stream>>>(psum, pcnt, Wlin, blin, out);
}